// Round 17
// baseline (108.729 us; speedup 1.0000x reference)
//
#include <hip/hip_runtime.h>

#define NN  100000
#define NE  600000
#define D   128
#define CAP 32     // bucket capacity; Poisson(6) in-degree, P(deg>=32)~1e-13/node

typedef __bf16 bf16x8 __attribute__((ext_vector_type(8)));
typedef __bf16 bf16x4 __attribute__((ext_vector_type(4)));
typedef float  f32x4  __attribute__((ext_vector_type(4)));

#define GB_FILL ((NE + 255) / 256)     // 2344 blocks: 1 edge/thread
#define GB_WP   8                      // w-prep blocks
#define GB_GEMM ((NN / 16 + 3) / 4)    // 1563 blocks: gemm tiles

__device__ inline float bflo(unsigned int v) {
    unsigned int t = v << 16; float f; __builtin_memcpy(&f, &t, 4); return f;
}
__device__ inline float bfhi(unsigned int v) {
    unsigned int t = v & 0xffff0000u; float f; __builtin_memcpy(&f, &t, 4); return f;
}

// ------------------------------------------------ kA: bucket-fill ∥ pack W->wf ∥ zero g row
// Fill first: it's the long pole and depends only on memset(cnt).
__global__ __launch_bounds__(256) void kA(const int* __restrict__ src,
                                          const int* __restrict__ dst,
                                          int* __restrict__ cnt,
                                          int* __restrict__ adj,
                                          const float* __restrict__ W,
                                          __bf16* __restrict__ wf,
                                          __bf16* __restrict__ g) {
    if (blockIdx.x < GB_FILL) {
        int e = blockIdx.x * 256 + threadIdx.x;
        if (e >= NE) return;
        int d = dst[e], s = src[e];
        if ((unsigned)d >= (unsigned)NN || (unsigned)s >= (unsigned)NN) return;
        int slot = atomicAdd(&cnt[d], 1);
        if (slot < CAP) adj[(d << 5) + slot] = s;
    } else {
        int t = (blockIdx.x - GB_FILL) * 256 + threadIdx.x;   // 0..2047
        if (t < D) g[(size_t)NN * D + t] = (__bf16)0.f;       // zero row for masked gathers
        int lane = t & 63, ct = (t >> 6) & 7, kt = t >> 9;
        int col = ct * 16 + (lane & 15);
        int k0  = kt * 32 + ((lane >> 4) & 3) * 8;
        const float* wp = W + col * D + k0;
        __bf16* o = wf + (size_t)t * 8;
        #pragma unroll
        for (int j = 0; j < 8; ++j) o[j] = (__bf16)wp[j];
    }
}

// ------------------------------------------------ k_gemm: g = dinv[row] * (x @ W.T), PRE-SCALED
// cnt is final (fill done), so the src-side norm folds into the GEMM epilogue.
// 16 lanes read 16 consecutive cnt ints -> coalesced; one rsqrt per output node.
__global__ __launch_bounds__(256) void k_gemm(const float* __restrict__ x,
                                              const __bf16* __restrict__ wf,
                                              const int* __restrict__ cnt,
                                              __bf16* __restrict__ g) {
    int gid = blockIdx.x * 4 + (threadIdx.x >> 6);
    if (gid >= NN / 16) return;                   // 6250 tiles
    int lane = threadIdx.x & 63;
    int l4   = lane & 15;
    int kg   = lane >> 4;
    int node = gid * 16 + l4;

    f32x4 acc[8];
    #pragma unroll
    for (int ct = 0; ct < 8; ++ct) acc[ct] = (f32x4){0.f, 0.f, 0.f, 0.f};

    #pragma unroll
    for (int kt = 0; kt < 4; ++kt) {
        const float4* xp = (const float4*)(x + (size_t)node * D + kt * 32 + kg * 8);
        float4 x0 = xp[0];
        float4 x1 = xp[1];
        bf16x8 a;
        a[0] = (__bf16)x0.x; a[1] = (__bf16)x0.y; a[2] = (__bf16)x0.z; a[3] = (__bf16)x0.w;
        a[4] = (__bf16)x1.x; a[5] = (__bf16)x1.y; a[6] = (__bf16)x1.z; a[7] = (__bf16)x1.w;
        const bf16x8* wfp = (const bf16x8*)wf + (size_t)kt * 512 + lane;
        #pragma unroll
        for (int ct = 0; ct < 8; ++ct) {
            bf16x8 b = wfp[ct * 64];
            acc[ct] = __builtin_amdgcn_mfma_f32_16x16x32_bf16(b, a, acc[ct], 0, 0, 0);
        }
    }

    float dv = rsqrtf((float)(cnt[node] + 1));    // pre-scale by dinv[row]
    #pragma unroll
    for (int ct = 0; ct < 8; ++ct) {
        bf16x4 o;
        #pragma unroll
        for (int i = 0; i < 4; ++i) o[i] = (__bf16)(acc[ct][i] * dv);
        *(bf16x4*)(g + (size_t)node * D + ct * 16 + kg * 4) = o;
    }
}

// ------------------------------------------------ k_agg: LEAN gather-aggregate, 4 nodes/wave
// g is pre-scaled -> per neighbor: gather + add ONLY. No cnt[s] reads, no per-neighbor
// rsqrt. Head-8 masked to dummy node NN (zero row). Runs immediately after gemm: g L2-hot.
__global__ __launch_bounds__(256) void k_agg(const float* __restrict__ x,
                                             const __bf16* __restrict__ g,
                                             const int* __restrict__ cnt,
                                             const float* __restrict__ bias,
                                             const int* __restrict__ adj,
                                             float* __restrict__ out) {
    int wave = blockIdx.x * 4 + (threadIdx.x >> 6);
    int lane = threadIdx.x & 63;
    int q    = lane >> 4;            // 0..3
    int l4   = lane & 15;
    int node = wave * 4 + q;         // < NN
    int c0   = l4 * 8;               // bf16 feature base

    int deg = cnt[node];
    int end = min(deg, CAP);
    float dv = rsqrtf((float)(deg + 1));
    const int* ap = adj + (node << 5);

    // bucket head: one 128B line; slots >= end masked to dummy node NN (zero row)
    int4 b0 = *(const int4*)ap;
    int4 b1 = *(const int4*)(ap + 4);
    int s0 = (end > 0) ? b0.x : NN;
    int s1 = (end > 1) ? b0.y : NN;
    int s2 = (end > 2) ? b0.z : NN;
    int s3 = (end > 3) ? b0.w : NN;
    int s4 = (end > 4) ? b1.x : NN;
    int s5 = (end > 5) ? b1.y : NN;
    int s6 = (end > 6) ? b1.z : NN;
    int s7 = (end > 7) ? b1.w : NN;

    uint4 u  = *(const uint4*)(g + (size_t)node * D + c0);   // self loop (pre-scaled)
    uint4 v0 = *(const uint4*)(g + (size_t)s0 * D + c0);
    uint4 v1 = *(const uint4*)(g + (size_t)s1 * D + c0);
    uint4 v2 = *(const uint4*)(g + (size_t)s2 * D + c0);
    uint4 v3 = *(const uint4*)(g + (size_t)s3 * D + c0);
    uint4 v4 = *(const uint4*)(g + (size_t)s4 * D + c0);
    uint4 v5 = *(const uint4*)(g + (size_t)s5 * D + c0);
    uint4 v6 = *(const uint4*)(g + (size_t)s6 * D + c0);
    uint4 v7 = *(const uint4*)(g + (size_t)s7 * D + c0);

    const float4* xp = (const float4*)(x + (size_t)node * D + c0);
    float4 xv0 = xp[0], xv1 = xp[1];
    const float4* bp = (const float4*)(bias + c0);
    float4 bv0 = bp[0], bv1 = bp[1];

    float a0 = bflo(u.x), a1 = bfhi(u.x), a2 = bflo(u.y), a3 = bfhi(u.y);
    float a4 = bflo(u.z), a5 = bfhi(u.z), a6 = bflo(u.w), a7 = bfhi(u.w);

    a0 += bflo(v0.x); a1 += bfhi(v0.x); a2 += bflo(v0.y); a3 += bfhi(v0.y);
    a4 += bflo(v0.z); a5 += bfhi(v0.z); a6 += bflo(v0.w); a7 += bfhi(v0.w);
    a0 += bflo(v1.x); a1 += bfhi(v1.x); a2 += bflo(v1.y); a3 += bfhi(v1.y);
    a4 += bflo(v1.z); a5 += bfhi(v1.z); a6 += bflo(v1.w); a7 += bfhi(v1.w);
    a0 += bflo(v2.x); a1 += bfhi(v2.x); a2 += bflo(v2.y); a3 += bfhi(v2.y);
    a4 += bflo(v2.z); a5 += bfhi(v2.z); a6 += bflo(v2.w); a7 += bfhi(v2.w);
    a0 += bflo(v3.x); a1 += bfhi(v3.x); a2 += bflo(v3.y); a3 += bfhi(v3.y);
    a4 += bflo(v3.z); a5 += bfhi(v3.z); a6 += bflo(v3.w); a7 += bfhi(v3.w);
    a0 += bflo(v4.x); a1 += bfhi(v4.x); a2 += bflo(v4.y); a3 += bfhi(v4.y);
    a4 += bflo(v4.z); a5 += bfhi(v4.z); a6 += bflo(v4.w); a7 += bfhi(v4.w);
    a0 += bflo(v5.x); a1 += bfhi(v5.x); a2 += bflo(v5.y); a3 += bfhi(v5.y);
    a4 += bflo(v5.z); a5 += bfhi(v5.z); a6 += bflo(v5.w); a7 += bfhi(v5.w);
    a0 += bflo(v6.x); a1 += bfhi(v6.x); a2 += bflo(v6.y); a3 += bfhi(v6.y);
    a4 += bflo(v6.z); a5 += bfhi(v6.z); a6 += bflo(v6.w); a7 += bfhi(v6.w);
    a0 += bflo(v7.x); a1 += bfhi(v7.x); a2 += bflo(v7.y); a3 += bfhi(v7.y);
    a4 += bflo(v7.z); a5 += bfhi(v7.z); a6 += bflo(v7.w); a7 += bfhi(v7.w);

    // tail: deg > 8 (~15% of nodes)
    for (int i = 8; i < end; i += 4) {
        int t0 = ap[i];
        int t1 = (i + 1 < end) ? ap[i + 1] : NN;
        int t2 = (i + 2 < end) ? ap[i + 2] : NN;
        int t3 = (i + 3 < end) ? ap[i + 3] : NN;
        uint4 y0 = *(const uint4*)(g + (size_t)t0 * D + c0);
        uint4 y1 = *(const uint4*)(g + (size_t)t1 * D + c0);
        uint4 y2 = *(const uint4*)(g + (size_t)t2 * D + c0);
        uint4 y3 = *(const uint4*)(g + (size_t)t3 * D + c0);
        a0 += bflo(y0.x); a1 += bfhi(y0.x); a2 += bflo(y0.y); a3 += bfhi(y0.y);
        a4 += bflo(y0.z); a5 += bfhi(y0.z); a6 += bflo(y0.w); a7 += bfhi(y0.w);
        a0 += bflo(y1.x); a1 += bfhi(y1.x); a2 += bflo(y1.y); a3 += bfhi(y1.y);
        a4 += bflo(y1.z); a5 += bfhi(y1.z); a6 += bflo(y1.w); a7 += bfhi(y1.w);
        a0 += bflo(y2.x); a1 += bfhi(y2.x); a2 += bflo(y2.y); a3 += bfhi(y2.y);
        a4 += bflo(y2.z); a5 += bfhi(y2.z); a6 += bflo(y2.w); a7 += bfhi(y2.w);
        a0 += bflo(y3.x); a1 += bfhi(y3.x); a2 += bflo(y3.y); a3 += bfhi(y3.y);
        a4 += bflo(y3.z); a5 += bfhi(y3.z); a6 += bflo(y3.w); a7 += bfhi(y3.w);
    }

    f32x4 r0, r1;
    r0[0] = xv0.x + fmaxf(fmaf(dv, a0, bv0.x), 0.f);
    r0[1] = xv0.y + fmaxf(fmaf(dv, a1, bv0.y), 0.f);
    r0[2] = xv0.z + fmaxf(fmaf(dv, a2, bv0.z), 0.f);
    r0[3] = xv0.w + fmaxf(fmaf(dv, a3, bv0.w), 0.f);
    r1[0] = xv1.x + fmaxf(fmaf(dv, a4, bv1.x), 0.f);
    r1[1] = xv1.y + fmaxf(fmaf(dv, a5, bv1.y), 0.f);
    r1[2] = xv1.z + fmaxf(fmaf(dv, a6, bv1.z), 0.f);
    r1[3] = xv1.w + fmaxf(fmaf(dv, a7, bv1.w), 0.f);
    f32x4* op = (f32x4*)(out + (size_t)node * D + c0);
    __builtin_nontemporal_store(r0, op);
    __builtin_nontemporal_store(r1, op + 1);
}

// ------------------------------------------------ launch
extern "C" void kernel_launch(void* const* d_in, const int* in_sizes, int n_in,
                              void* d_out, int out_size, void* d_ws, size_t ws_size,
                              hipStream_t stream) {
    const float* x    = (const float*)d_in[0];
    const int*   ei   = (const int*)d_in[1];      // [2][NE], int32
    const float* W    = (const float*)d_in[2];    // [D][D]
    const float* bias = (const float*)d_in[3];    // [D]
    float* out = (float*)d_out;

    const int* src = ei;
    const int* dst = ei + NE;

    char* p = (char*)d_ws;
    auto take = [&](size_t bytes) {
        char* q = p;
        p += (bytes + 255) & ~(size_t)255;
        return q;
    };
    int*    cnt = (int*)take((size_t)(NN + 1) * 4);        // cnt[NN]=0 for dummy node
    int*    adj = (int*)take((size_t)NN * CAP * 4);        // 12.8 MB buckets
    __bf16* wf  = (__bf16*)take((size_t)2048 * 8 * 2);
    __bf16* g   = (__bf16*)take((size_t)(NN + 1) * D * 2); // +1 zero row

    (void)hipMemsetAsync(cnt, 0, (size_t)(NN + 1) * 4, stream);

    kA    <<<GB_FILL + GB_WP, 256, 0, stream>>>(src, dst, cnt, adj, W, wf, g);
    k_gemm<<<GB_GEMM, 256, 0, stream>>>(x, wf, cnt, g);
    k_agg <<<NN / 16, 256, 0, stream>>>(x, g, cnt, bias, adj, out);
}

// Round 18
// 84.175 us; speedup vs baseline: 1.2917x; 1.2917x over previous
//
#include <hip/hip_runtime.h>

#define NN  100000
#define NE  600000
#define D   128
#define CAP 32     // bucket capacity; Poisson(6) in-degree, P(deg>=32)~1e-13/node

typedef __bf16 bf16x8 __attribute__((ext_vector_type(8)));
typedef __bf16 bf16x4 __attribute__((ext_vector_type(4)));
typedef float  f32x4  __attribute__((ext_vector_type(4)));

#define GB_Z    ((NN + 1 + 255) / 256)   // 391 blocks: zero cnt
#define GB_WP   8                        // w-prep blocks
#define K1_GRID (782 * 7)                // 5474: stripes of {4 gemm, 3 fill}
                                         // gemm: 3125 blocks = 12500 half-tile waves (2x TLP)
                                         // fill: 2344 blocks

__device__ inline float bflo(unsigned int v) {
    unsigned int t = v << 16; float f; __builtin_memcpy(&f, &t, 4); return f;
}
__device__ inline float bfhi(unsigned int v) {
    unsigned int t = v & 0xffff0000u; float f; __builtin_memcpy(&f, &t, 4); return f;
}

// ------------------------------------------------ k0: zero cnt ∥ pack W->wf ∥ zero g row
// wf slot t = kt*512 + ct*64 + lane holds W[col][k0..k0+7] bf16,
// col = ct*16+(lane&15), k0 = kt*32+((lane>>4)&3)*8
__global__ __launch_bounds__(256) void k0(int* __restrict__ cnt,
                                          const float* __restrict__ W,
                                          __bf16* __restrict__ wf,
                                          __bf16* __restrict__ g) {
    if (blockIdx.x < GB_Z) {
        int i = blockIdx.x * 256 + threadIdx.x;
        if (i <= NN) cnt[i] = 0;                         // includes dummy cnt[NN]=0
    } else {
        int t = (blockIdx.x - GB_Z) * 256 + threadIdx.x; // 0..2047
        if (t < D) g[(size_t)NN * D + t] = (__bf16)0.f;  // zero row for masked gathers
        int lane = t & 63, ct = (t >> 6) & 7, kt = t >> 9;
        int col = ct * 16 + (lane & 15);
        int k0  = kt * 32 + ((lane >> 4) & 3) * 8;
        const float* wp = W + col * D + k0;
        __bf16* o = wf + (size_t)t * 8;
        #pragma unroll
        for (int j = 0; j < 8; ++j) o[j] = (__bf16)wp[j];
    }
}

// ------------------------------------------------ k1: gemm (HALF-TILE waves) ∥ bucket-fill
// R11's fused structure (best timed config: fill+gemm writes leave adj/cnt/g L2-hot for
// k_agg). Change: each 16-node tile is split into TWO waves by output-column half
// (ct 0-3 / 4-7) -> 12500 gemm waves (~3/SIMD) instead of 6252 (~1.5/SIMD), doubling
// the TLP that hides x-load (HBM ~900cy) and wf-load (L2 ~200cy) latency.
__global__ __launch_bounds__(256) void k1(const float* __restrict__ x,
                                          const __bf16* __restrict__ wf,
                                          const int* __restrict__ src,
                                          const int* __restrict__ dst,
                                          int* __restrict__ cnt,
                                          int* __restrict__ adj,
                                          __bf16* __restrict__ g) {
    int r  = blockIdx.x % 7;
    int gq = blockIdx.x / 7;
    if (r < 4) {
        int blk = gq * 4 + r;                         // 0..3127
        int job = blk * 4 + (threadIdx.x >> 6);       // half-tile job
        if (job >= 12500) return;                     // 6250 tiles x 2 halves
        int tile = job >> 1;
        int ch   = job & 1;                           // column half: ct = ch*4 .. ch*4+3
        int lane = threadIdx.x & 63;
        int l4   = lane & 15;
        int kg   = lane >> 4;
        int node = tile * 16 + l4;

        f32x4 acc[4];
        #pragma unroll
        for (int c = 0; c < 4; ++c) acc[c] = (f32x4){0.f, 0.f, 0.f, 0.f};

        #pragma unroll
        for (int kt = 0; kt < 4; ++kt) {
            const float4* xp = (const float4*)(x + (size_t)node * D + kt * 32 + kg * 8);
            float4 x0 = xp[0];
            float4 x1 = xp[1];
            bf16x8 a;
            a[0] = (__bf16)x0.x; a[1] = (__bf16)x0.y; a[2] = (__bf16)x0.z; a[3] = (__bf16)x0.w;
            a[4] = (__bf16)x1.x; a[5] = (__bf16)x1.y; a[6] = (__bf16)x1.z; a[7] = (__bf16)x1.w;
            const bf16x8* wfp = (const bf16x8*)wf + (size_t)kt * 512 + ch * 256 + lane;
            #pragma unroll
            for (int c = 0; c < 4; ++c) {
                bf16x8 b = wfp[c * 64];
                acc[c] = __builtin_amdgcn_mfma_f32_16x16x32_bf16(b, a, acc[c], 0, 0, 0);
            }
        }

        // C/D layout: col(l4)=node, rows kg*4..kg*4+3 = features -> bf16x4 stores
        #pragma unroll
        for (int c = 0; c < 4; ++c) {
            bf16x4 o;
            #pragma unroll
            for (int i = 0; i < 4; ++i) o[i] = (__bf16)acc[c][i];
            *(bf16x4*)(g + (size_t)node * D + (ch * 4 + c) * 16 + kg * 4) = o;
        }
    } else {
        int blk = gq * 3 + (r - 4);                   // 0..2345
        int e = blk * 256 + threadIdx.x;
        if (e >= NE) return;
        int d = dst[e], s = src[e];
        if ((unsigned)d >= (unsigned)NN || (unsigned)s >= (unsigned)NN) return;
        int slot = atomicAdd(&cnt[d], 1);
        if (slot < CAP) adj[(d << 5) + slot] = s;
    }
}

// ------------------------------------------------ k_agg: gather-aggregate, 4 nodes/wave
// (exact R11 form) First 8 bucket slots loaded unconditionally; tail loop for deg>8.
// Dummy s=NN: cnt[NN]=0, g row NN = 0.
__global__ __launch_bounds__(256) void k_agg(const float* __restrict__ x,
                                             const __bf16* __restrict__ g,
                                             const int* __restrict__ cnt,
                                             const float* __restrict__ bias,
                                             const int* __restrict__ adj,
                                             float* __restrict__ out) {
    int wave = blockIdx.x * 4 + (threadIdx.x >> 6);
    int lane = threadIdx.x & 63;
    int q    = lane >> 4;            // 0..3
    int l4   = lane & 15;
    int node = wave * 4 + q;         // < NN
    int c0   = l4 * 8;               // bf16 feature base

    int deg = cnt[node];
    int end = min(deg, CAP);
    float dv = rsqrtf((float)(deg + 1));
    const int* ap = adj + (node << 5);

    int4 b0 = *(const int4*)ap;
    int4 b1 = *(const int4*)(ap + 4);
    int s0 = (end > 0) ? b0.x : NN;
    int s1 = (end > 1) ? b0.y : NN;
    int s2 = (end > 2) ? b0.z : NN;
    int s3 = (end > 3) ? b0.w : NN;
    int s4 = (end > 4) ? b1.x : NN;
    int s5 = (end > 5) ? b1.y : NN;
    int s6 = (end > 6) ? b1.z : NN;
    int s7 = (end > 7) ? b1.w : NN;

    const float4* xp = (const float4*)(x + (size_t)node * D + c0);
    float4 xv0 = xp[0], xv1 = xp[1];
    const float4* bp = (const float4*)(bias + c0);
    float4 bv0 = bp[0], bv1 = bp[1];

    uint4 u = *(const uint4*)(g + (size_t)node * D + c0);   // self loop
    int n0 = cnt[s0], n1 = cnt[s1], n2 = cnt[s2], n3 = cnt[s3];
    int n4 = cnt[s4], n5 = cnt[s5], n6 = cnt[s6], n7 = cnt[s7];
    uint4 v0 = *(const uint4*)(g + (size_t)s0 * D + c0);
    uint4 v1 = *(const uint4*)(g + (size_t)s1 * D + c0);
    uint4 v2 = *(const uint4*)(g + (size_t)s2 * D + c0);
    uint4 v3 = *(const uint4*)(g + (size_t)s3 * D + c0);
    uint4 v4 = *(const uint4*)(g + (size_t)s4 * D + c0);
    uint4 v5 = *(const uint4*)(g + (size_t)s5 * D + c0);
    uint4 v6 = *(const uint4*)(g + (size_t)s6 * D + c0);
    uint4 v7 = *(const uint4*)(g + (size_t)s7 * D + c0);

    float a0 = dv * bflo(u.x), a1 = dv * bfhi(u.x), a2 = dv * bflo(u.y), a3 = dv * bfhi(u.y);
    float a4 = dv * bflo(u.z), a5 = dv * bfhi(u.z), a6 = dv * bflo(u.w), a7 = dv * bfhi(u.w);

    float w0 = rsqrtf((float)(n0 + 1)), w1 = rsqrtf((float)(n1 + 1));
    float w2 = rsqrtf((float)(n2 + 1)), w3 = rsqrtf((float)(n3 + 1));
    float w4 = rsqrtf((float)(n4 + 1)), w5 = rsqrtf((float)(n5 + 1));
    float w6 = rsqrtf((float)(n6 + 1)), w7 = rsqrtf((float)(n7 + 1));

    a0 += w0 * bflo(v0.x); a1 += w0 * bfhi(v0.x); a2 += w0 * bflo(v0.y); a3 += w0 * bfhi(v0.y);
    a4 += w0 * bflo(v0.z); a5 += w0 * bfhi(v0.z); a6 += w0 * bflo(v0.w); a7 += w0 * bfhi(v0.w);
    a0 += w1 * bflo(v1.x); a1 += w1 * bfhi(v1.x); a2 += w1 * bflo(v1.y); a3 += w1 * bfhi(v1.y);
    a4 += w1 * bflo(v1.z); a5 += w1 * bfhi(v1.z); a6 += w1 * bflo(v1.w); a7 += w1 * bfhi(v1.w);
    a0 += w2 * bflo(v2.x); a1 += w2 * bfhi(v2.x); a2 += w2 * bflo(v2.y); a3 += w2 * bfhi(v2.y);
    a4 += w2 * bflo(v2.z); a5 += w2 * bfhi(v2.z); a6 += w2 * bflo(v2.w); a7 += w2 * bfhi(v2.w);
    a0 += w3 * bflo(v3.x); a1 += w3 * bfhi(v3.x); a2 += w3 * bflo(v3.y); a3 += w3 * bfhi(v3.y);
    a4 += w3 * bflo(v3.z); a5 += w3 * bfhi(v3.z); a6 += w3 * bflo(v3.w); a7 += w3 * bfhi(v3.w);
    a0 += w4 * bflo(v4.x); a1 += w4 * bfhi(v4.x); a2 += w4 * bflo(v4.y); a3 += w4 * bfhi(v4.y);
    a4 += w4 * bflo(v4.z); a5 += w4 * bfhi(v4.z); a6 += w4 * bflo(v4.w); a7 += w4 * bfhi(v4.w);
    a0 += w5 * bflo(v5.x); a1 += w5 * bfhi(v5.x); a2 += w5 * bflo(v5.y); a3 += w5 * bfhi(v5.y);
    a4 += w5 * bflo(v5.z); a5 += w5 * bfhi(v5.z); a6 += w5 * bflo(v5.w); a7 += w5 * bfhi(v5.w);
    a0 += w6 * bflo(v6.x); a1 += w6 * bfhi(v6.x); a2 += w6 * bflo(v6.y); a3 += w6 * bfhi(v6.y);
    a4 += w6 * bflo(v6.z); a5 += w6 * bfhi(v6.z); a6 += w6 * bflo(v6.w); a7 += w6 * bfhi(v6.w);
    a0 += w7 * bflo(v7.x); a1 += w7 * bfhi(v7.x); a2 += w7 * bflo(v7.y); a3 += w7 * bfhi(v7.y);
    a4 += w7 * bflo(v7.z); a5 += w7 * bfhi(v7.z); a6 += w7 * bflo(v7.w); a7 += w7 * bfhi(v7.w);

    // tail: deg > 8 (~15% of nodes)
    for (int i = 8; i < end; i += 4) {
        int t0 = ap[i];
        int t1 = (i + 1 < end) ? ap[i + 1] : NN;
        int t2 = (i + 2 < end) ? ap[i + 2] : NN;
        int t3 = (i + 3 < end) ? ap[i + 3] : NN;
        int m0 = cnt[t0], m1 = cnt[t1], m2 = cnt[t2], m3 = cnt[t3];
        uint4 y0 = *(const uint4*)(g + (size_t)t0 * D + c0);
        uint4 y1 = *(const uint4*)(g + (size_t)t1 * D + c0);
        uint4 y2 = *(const uint4*)(g + (size_t)t2 * D + c0);
        uint4 y3 = *(const uint4*)(g + (size_t)t3 * D + c0);
        float z0 = rsqrtf((float)(m0 + 1));
        float z1 = rsqrtf((float)(m1 + 1));
        float z2 = rsqrtf((float)(m2 + 1));
        float z3 = rsqrtf((float)(m3 + 1));
        a0 += z0 * bflo(y0.x); a1 += z0 * bfhi(y0.x); a2 += z0 * bflo(y0.y); a3 += z0 * bfhi(y0.y);
        a4 += z0 * bflo(y0.z); a5 += z0 * bfhi(y0.z); a6 += z0 * bflo(y0.w); a7 += z0 * bfhi(y0.w);
        a0 += z1 * bflo(y1.x); a1 += z1 * bfhi(y1.x); a2 += z1 * bflo(y1.y); a3 += z1 * bfhi(y1.y);
        a4 += z1 * bflo(y1.z); a5 += z1 * bfhi(y1.z); a6 += z1 * bflo(y1.w); a7 += z1 * bfhi(y1.w);
        a0 += z2 * bflo(y2.x); a1 += z2 * bfhi(y2.x); a2 += z2 * bflo(y2.y); a3 += z2 * bfhi(y2.y);
        a4 += z2 * bflo(y2.z); a5 += z2 * bfhi(y2.z); a6 += z2 * bflo(y2.w); a7 += z2 * bfhi(y2.w);
        a0 += z3 * bflo(y3.x); a1 += z3 * bfhi(y3.x); a2 += z3 * bflo(y3.y); a3 += z3 * bfhi(y3.y);
        a4 += z3 * bflo(y3.z); a5 += z3 * bfhi(y3.z); a6 += z3 * bflo(y3.w); a7 += z3 * bfhi(y3.w);
    }

    f32x4 r0, r1;
    r0[0] = xv0.x + fmaxf(fmaf(dv, a0, bv0.x), 0.f);
    r0[1] = xv0.y + fmaxf(fmaf(dv, a1, bv0.y), 0.f);
    r0[2] = xv0.z + fmaxf(fmaf(dv, a2, bv0.z), 0.f);
    r0[3] = xv0.w + fmaxf(fmaf(dv, a3, bv0.w), 0.f);
    r1[0] = xv1.x + fmaxf(fmaf(dv, a4, bv1.x), 0.f);
    r1[1] = xv1.y + fmaxf(fmaf(dv, a5, bv1.y), 0.f);
    r1[2] = xv1.z + fmaxf(fmaf(dv, a6, bv1.z), 0.f);
    r1[3] = xv1.w + fmaxf(fmaf(dv, a7, bv1.w), 0.f);
    f32x4* op = (f32x4*)(out + (size_t)node * D + c0);
    __builtin_nontemporal_store(r0, op);
    __builtin_nontemporal_store(r1, op + 1);
}

// ------------------------------------------------ launch
extern "C" void kernel_launch(void* const* d_in, const int* in_sizes, int n_in,
                              void* d_out, int out_size, void* d_ws, size_t ws_size,
                              hipStream_t stream) {
    const float* x    = (const float*)d_in[0];
    const int*   ei   = (const int*)d_in[1];      // [2][NE], int32
    const float* W    = (const float*)d_in[2];    // [D][D]
    const float* bias = (const float*)d_in[3];    // [D]
    float* out = (float*)d_out;

    const int* src = ei;
    const int* dst = ei + NE;

    char* p = (char*)d_ws;
    auto take = [&](size_t bytes) {
        char* q = p;
        p += (bytes + 255) & ~(size_t)255;
        return q;
    };
    int*    cnt = (int*)take((size_t)(NN + 1) * 4);        // cnt[NN]=0 for dummy node
    int*    adj = (int*)take((size_t)NN * CAP * 4);        // 12.8 MB buckets
    __bf16* wf  = (__bf16*)take((size_t)2048 * 8 * 2);
    __bf16* g   = (__bf16*)take((size_t)(NN + 1) * D * 2); // +1 zero row

    k0   <<<GB_Z + GB_WP, 256, 0, stream>>>(cnt, W, wf, g);
    k1   <<<K1_GRID, 256, 0, stream>>>(x, wf, src, dst, cnt, adj, g);
    k_agg<<<NN / 16, 256, 0, stream>>>(x, g, cnt, bias, adj, out);
}